// Round 3
// baseline (11.730 us; speedup 1.0000x reference)
//
#include <hip/hip_runtime.h>

// Haar(10 levels, 1023 feats) -> MLP 1023->8->8->3, single fused kernel.
//
// All Haar edges are multiples of 2^-10, so the mask vector depends only on
// u = floor(t*1024) (exact in f32: power-of-2 scale, 0 <= t < 1).
// Level j: row = 2^j - 1 + (u >> (10-j)); sign = +1 if bit (9-j) of u is 0
// (left half-interval) else -1. Verified exact vs reference in rounds 1-2
// (absmax 0.0).
//
// Structure note (R2 post-mortem): per-replay floor is ~9.5 us; a second
// dependent kernel launch costs +1.4 us — keep everything in ONE kernel.

__global__ __launch_bounds__(256) void haar_mlp_kernel(
    const float* __restrict__ t,
    const float* __restrict__ W1, const float* __restrict__ b1,
    const float* __restrict__ W2, const float* __restrict__ b2,
    const float* __restrict__ W3, const float* __restrict__ b3,
    float* __restrict__ out, int n)
{
    // W1: 1023 rows x 8 floats = 2046 float4 = 32736 B of LDS
    __shared__ float4 w1s[2046];
    #pragma unroll
    for (int s = 0; s < 8; ++s) {
        int idx = (int)threadIdx.x + s * 256;
        if (idx < 2046) w1s[idx] = reinterpret_cast<const float4*>(W1)[idx];
    }
    __syncthreads();

    int i = blockIdx.x * 256 + (int)threadIdx.x;
    if (i >= n) return;

    float tv = t[i];
    int u = (int)(tv * 1024.0f);
    u = (u < 0) ? 0 : (u > 1023 ? 1023 : u);

    float h1[8];
    #pragma unroll
    for (int o = 0; o < 8; ++o) h1[o] = b1[o];

    #pragma unroll
    for (int j = 0; j < 10; ++j) {
        int row = (1 << j) - 1 + (u >> (10 - j));
        float sgn = ((u >> (9 - j)) & 1) ? -1.0f : 1.0f;
        float4 lo = w1s[row * 2 + 0];
        float4 hi = w1s[row * 2 + 1];
        h1[0] = fmaf(sgn, lo.x, h1[0]); h1[1] = fmaf(sgn, lo.y, h1[1]);
        h1[2] = fmaf(sgn, lo.z, h1[2]); h1[3] = fmaf(sgn, lo.w, h1[3]);
        h1[4] = fmaf(sgn, hi.x, h1[4]); h1[5] = fmaf(sgn, hi.y, h1[5]);
        h1[6] = fmaf(sgn, hi.z, h1[6]); h1[7] = fmaf(sgn, hi.w, h1[7]);
    }
    #pragma unroll
    for (int o = 0; o < 8; ++o) h1[o] = fmaxf(h1[o], 0.0f);

    // h2 = relu(h1 @ W2 + b2); W2 (8,8) row-major, uniform -> s_load
    float h2[8];
    #pragma unroll
    for (int o = 0; o < 8; ++o) {
        float a = b2[o];
        #pragma unroll
        for (int q = 0; q < 8; ++q) a = fmaf(h1[q], W2[q * 8 + o], a);
        h2[o] = fmaxf(a, 0.0f);
    }

    // out = h2 @ W3 + b3; W3 (8,3)
    float o0 = b3[0], o1 = b3[1], o2 = b3[2];
    #pragma unroll
    for (int q = 0; q < 8; ++q) {
        o0 = fmaf(h2[q], W3[q * 3 + 0], o0);
        o1 = fmaf(h2[q], W3[q * 3 + 1], o1);
        o2 = fmaf(h2[q], W3[q * 3 + 2], o2);
    }
    out[i * 3 + 0] = o0;
    out[i * 3 + 1] = o1;
    out[i * 3 + 2] = o2;
}

extern "C" void kernel_launch(void* const* d_in, const int* in_sizes, int n_in,
                              void* d_out, int out_size, void* d_ws, size_t ws_size,
                              hipStream_t stream) {
    const float* t  = (const float*)d_in[0];
    const float* W1 = (const float*)d_in[1];
    const float* b1 = (const float*)d_in[2];
    const float* W2 = (const float*)d_in[3];
    const float* b2 = (const float*)d_in[4];
    const float* W3 = (const float*)d_in[5];
    const float* b3 = (const float*)d_in[6];
    float* out = (float*)d_out;

    int n = in_sizes[0];  // B*T = 131072
    haar_mlp_kernel<<<(n + 255) / 256, 256, 0, stream>>>(t, W1, b1, W2, b2, W3, b3, out, n);
}